// Round 14
// baseline (323.397 us; speedup 1.0000x reference)
//
#include <hip/hip_runtime.h>
#include <hip/hip_bf16.h>

#define BATCH 4
#define CDIM  256
#define NTOK  4096
#define THREE (3*CDIM)
#define VROWS 272   // 256 V channels + fg row at 256 (257..271 unused)

typedef unsigned short u16;
typedef unsigned char u8;
typedef long i64;
typedef __attribute__((ext_vector_type(4))) float f32x4;
typedef __attribute__((ext_vector_type(8))) short bf16x8;
typedef __attribute__((ext_vector_type(4))) unsigned int u32x4;

#define AS1 __attribute__((address_space(1)))
#define AS3 __attribute__((address_space(3)))

__device__ __forceinline__ u16 f2bf(float x) {
  unsigned int u = __float_as_uint(x);
  unsigned int r = (u + 0x7fffu + ((u >> 16) & 1u)) >> 16;   // RTNE
  return (u16)r;
}
__device__ __forceinline__ float bf2f(u16 v) {
  return __uint_as_float(((unsigned int)v) << 16);
}
__device__ __forceinline__ u8 f2fp8(float x) {
  int r = __builtin_amdgcn_cvt_pk_fp8_f32(x, 0.0f, 0, false);  // e4m3 (OCP), RNE
  return (u8)(r & 0xff);
}
__device__ __forceinline__ void gload_lds16(const void* g, void* l) {
  __builtin_amdgcn_global_load_lds((AS1 const void*)g, (AS3 void*)l, 16, 0, 0);
}

// both Q and K carry sqrt(log2e/16) so (Q'.K') is directly in log2 domain
#define SC8 0.30028132f

// ---------------- K1: weights -> bf16; fg -> bf16 row in Vt ----------------
__global__ void k_prep(const float* __restrict__ Wqkv, const float* __restrict__ Wproj,
                       const int* __restrict__ fg,
                       u16* __restrict__ wq, u16* __restrict__ wp,
                       u16* __restrict__ Vt) {
  int i = blockIdx.x * 256 + threadIdx.x;
  const int nq = THREE * CDIM;          // 196608
  const int np = CDIM * CDIM;           // 65536
  const int nf = BATCH * NTOK;          // 16384 (fg row c=256)
  if (i < nq) { wq[i] = f2bf(Wqkv[i]); return; }
  int j = i - nq;
  if (j < np) { wp[j] = f2bf(Wproj[j]); return; }
  int k = j - np;
  if (k < nf) {
    int b = k >> 12, key = k & (NTOK - 1);
    Vt[((size_t)b * VROWS + 256) * NTOK + key] = fg[k] ? 0x3F80 : 0;  // bf16 1.0/0.0
  }
}

// ---------------- K2: x [B][C][N] f32 -> xbf [B][N][C] bf16 ----------------
__global__ __launch_bounds__(256) void k_transpose(const float* __restrict__ x, u16* __restrict__ xbf) {
  __shared__ u16 t[64][65];
  int n0 = blockIdx.x * 64;
  int c0 = blockIdx.y * 64;
  int b  = blockIdx.z;
  int tid = threadIdx.x;
  const float* xp = x + (size_t)b * CDIM * NTOK;
  int nl = tid & 63;
  int cb = tid >> 6;
#pragma unroll
  for (int i = 0; i < 16; ++i) {
    int cl = cb * 16 + i;
    t[nl][cl] = f2bf(xp[(size_t)(c0 + cl) * NTOK + n0 + nl]);
  }
  __syncthreads();
  int cl = tid & 63;
  int nb = tid >> 6;
  u16* op = xbf + ((size_t)b * NTOK + n0) * CDIM + c0;
#pragma unroll
  for (int i = 0; i < 16; ++i) {
    int nl2 = nb * 16 + i;
    op[(size_t)nl2 * CDIM + cl] = t[nl2][cl];
  }
}

// ---------------- K3: qkv GEMM. Q,K -> fp8 e4m3 (x SC8 each); V^T [c][key] bf16, fg-zeroed ----------------
__global__ __launch_bounds__(256) void k_qkv(const u16* __restrict__ xbf, const u16* __restrict__ wq,
                                             const int* __restrict__ fg,
                                             u8* __restrict__ Qm8, u8* __restrict__ Km8,
                                             u16* __restrict__ Vt) {
  __shared__ u16 Al[128][72];
  __shared__ u16 Bl[128][72];
  int n0 = blockIdx.x * 128;
  int d0 = blockIdx.y * 128;
  int b  = blockIdx.z;
  int tid = threadIdx.x;
  int lane = tid & 63, w = tid >> 6;
  int lo = lane & 15, hi = lane >> 4;
  int wm = w >> 1, wn = w & 1;
  f32x4 acc[4][4] = {};
  const u16* Ab = xbf + ((size_t)b * NTOK + n0) * CDIM;
  const u16* Bb = wq + (size_t)d0 * CDIM;
  for (int kc = 0; kc < 256; kc += 64) {
    __syncthreads();
#pragma unroll
    for (int i = 0; i < 4; ++i) {
      int cid = i * 256 + tid;
      int row = cid >> 3, cc = cid & 7;
      *(uint4*)&Al[row][cc * 8] = *(const uint4*)(Ab + (size_t)row * CDIM + kc + cc * 8);
      *(uint4*)&Bl[row][cc * 8] = *(const uint4*)(Bb + (size_t)row * CDIM + kc + cc * 8);
    }
    __syncthreads();
#pragma unroll
    for (int kk = 0; kk < 2; ++kk) {
      bf16x8 af[4], bfr[4];
#pragma unroll
      for (int mi = 0; mi < 4; ++mi) af[mi]  = *(const bf16x8*)&Al[wm * 64 + mi * 16 + lo][kk * 32 + hi * 8];
#pragma unroll
      for (int ni = 0; ni < 4; ++ni) bfr[ni] = *(const bf16x8*)&Bl[wn * 64 + ni * 16 + lo][kk * 32 + hi * 8];
#pragma unroll
      for (int mi = 0; mi < 4; ++mi)
#pragma unroll
        for (int ni = 0; ni < 4; ++ni)
          acc[mi][ni] = __builtin_amdgcn_mfma_f32_16x16x32_bf16(af[mi], bfr[ni], acc[mi][ni], 0, 0, 0);
    }
  }
  int seg = d0 >> 8;   // 0=Q 1=K 2=V
#pragma unroll
  for (int mi = 0; mi < 4; ++mi) {
    int nbase = n0 + wm * 64 + mi * 16 + hi * 4;
#pragma unroll
    for (int ni = 0; ni < 4; ++ni) {
      int d = d0 + wn * 64 + ni * 16 + lo;
      if (seg == 0) {
#pragma unroll
        for (int r = 0; r < 4; ++r)
          Qm8[((size_t)b * NTOK + nbase + r) * CDIM + d] = f2fp8(acc[mi][ni][r] * SC8);
      } else if (seg == 1) {
        int dk = d - 256;
#pragma unroll
        for (int r = 0; r < 4; ++r)
          Km8[((size_t)b * NTOK + nbase + r) * CDIM + dk] = f2fp8(acc[mi][ni][r] * SC8);
      } else {
        int dv = d - 512;
        ushort4 pk;
        pk.x = fg[b * NTOK + nbase + 0] ? f2bf(acc[mi][ni][0]) : (u16)0;
        pk.y = fg[b * NTOK + nbase + 1] ? f2bf(acc[mi][ni][1]) : (u16)0;
        pk.z = fg[b * NTOK + nbase + 2] ? f2bf(acc[mi][ni][2]) : (u16)0;
        pk.w = fg[b * NTOK + nbase + 3] ? f2bf(acc[mi][ni][3]) : (u16)0;
        *(ushort4*)&Vt[((size_t)b * VROWS + dv) * NTOK + nbase] = pk;
      }
    }
  }
}

// ---------------- K4: flash attention, fp8 QK + split-8 + 3 blocks/CU ----------------
// grid = 1024 blocks; 4 waves x 32 q-rows; KBLK=32; double-buffered staging; LDS 49KB.
// S^T = mfma_fp8(K',Q') directly in log2 domain; P^T in registers (cvt_pk+shfl);
// PV^T = mfma(V^T, P^T) bf16. Fixed max FM=12; mask via zeroed V rows; l = sum P*fg.
__global__ __launch_bounds__(256, 3) void k_attn(const u8* __restrict__ Qm8, const u8* __restrict__ Km8,
                                                 const u16* __restrict__ Vt,
                                                 u16* __restrict__ pacc, u16* __restrict__ pacc7,
                                                 float2* __restrict__ pml) {
  __shared__ u8  Kl[2][32 * 256];    // 8KB x2 fp8; 16B-chunk ^= (row&7)
  __shared__ u16 Vl[2][256 * 32];    // 16KB x2 bf16
  __shared__ u16 fgl[512];           // bf16 fg for this chunk's 512 keys
  const float FM = 12.0f;
  const int LSPLIT = 3;
  int nwg = gridDim.x;
  int cpx = nwg >> 3;
  int orig = blockIdx.x;
  int wg = (orig & 7) * cpx + (orig >> 3);   // bijective XCD swizzle (nwg % 8 == 0)
  int qt = wg & 31;
  int bs = wg >> 5;
  int s_k = bs & 7;
  int b   = bs >> LSPLIT;
  const int chunk = NTOK >> LSPLIT;          // 512
  int koff  = s_k * chunk;
  const int iters = chunk >> 5;              // 16

  int tid = threadIdx.x;
  int lane = tid & 63, w = tid >> 6;
  int lo = lane & 15, hi = lane >> 4;
  int n0 = qt * 128 + w * 32;
  // Q': 32 rows x 256 fp8 in registers (16 VGPR)
  i64 qf[2][8];
#pragma unroll
  for (int s = 0; s < 2; ++s) {
    const u8* qp = Qm8 + ((size_t)b * NTOK + n0 + s * 16 + lo) * CDIM + hi * 8;
#pragma unroll
    for (int ks = 0; ks < 8; ++ks) qf[s][ks] = *(const i64*)(qp + ks * 32);
  }
  f32x4 acc[2][16] = {};   // out^T: acc[s][cf][r] = out[d=cf*16+hi*4+r][q=s*16+lo]
  float lsum[2] = {0.0f, 0.0f};
  const u8*  kbase = Km8 + (size_t)b * NTOK * CDIM;
  const u16* vbase = Vt + (size_t)b * VROWS * NTOK;
  const u16* fgrow = vbase + (size_t)256 * NTOK;   // bf16 fg row
  int vr  = lane >> 2;   // V staging: row within 16-row group
  int vc  = lane & 3;
  int srcA = lo + ((hi & 1) << 5);   // P^T exchange source lanes
  int srcB = srcA + 16;

  // stage K (2 insts/wave, fp8) and V (4 insts/wave) for key-block m0 into buffer buf
  auto stage = [&](int buf, int m0) {
#pragma unroll
    for (int j = 0; j < 2; ++j) {
      int rl = w * 8 + j * 4 + (lane >> 4);          // row within 32-row tile
      int sb = ((lane & 15) << 4) ^ ((rl & 7) << 4); // source pre-swizzle (16B chunks)
      gload_lds16(kbase + (size_t)(m0 + rl) * CDIM + sb,
                  &Kl[buf][w * 2048 + j * 1024]);
    }
#pragma unroll
    for (int j = 0; j < 4; ++j) {
      int idx = j * 4 + w;                 // 0..15
      int r = idx * 16 + vr;
      int d = vc ^ (r & 3) ^ ((r >> 2) & 3);
      gload_lds16(vbase + (size_t)r * NTOK + m0 + d * 8, &Vl[buf][idx * 512]);
    }
  };

  // prologue: fg chunk (wave 0, one inst covers 1KB) + tile 0; barrier drains gload_lds
  if (w == 0) gload_lds16(fgrow + koff + lane * 8, &fgl[0]);
  stage(0, koff);
  __syncthreads();
  for (int it = 0; it < iters; ++it) {
    int cur = it & 1;
    int m0 = koff + it * 32;
    if (it + 1 < iters) stage(cur ^ 1, m0 + 32);   // prefetch next tile
    // S^T - FM: A = K' (fp8), B = Q' (fp8), scales pre-folded to log2 domain
    f32x4 sv[2][2];
#pragma unroll
    for (int s = 0; s < 2; ++s)
#pragma unroll
      for (int ni = 0; ni < 2; ++ni)
#pragma unroll
        for (int r = 0; r < 4; ++r) sv[s][ni][r] = -FM;
    __builtin_amdgcn_s_setprio(1);
#pragma unroll
    for (int ks = 0; ks < 8; ++ks) {
      i64 kf[2];
#pragma unroll
      for (int ni = 0; ni < 2; ++ni) {
        int row = ni * 16 + lo;
        int byteoff = row * 256 + ((((ks * 2 + (hi >> 1)) << 4) ^ ((row & 7) << 4))) + ((hi & 1) << 3);
        kf[ni] = *(const i64*)((const char*)&Kl[cur][0] + byteoff);
      }
#pragma unroll
      for (int s = 0; s < 2; ++s)
#pragma unroll
        for (int ni = 0; ni < 2; ++ni)
          sv[s][ni] = __builtin_amdgcn_mfma_f32_16x16x32_fp8_fp8(kf[ni], qf[s][ks], sv[s][ni], 0, 0, 0);
    }
    __builtin_amdgcn_s_setprio(0);
    // P = exp2(S^T - FM); lane covers keys {ni*16 + hi*4 + r} for q = s*16+lo.
    float p0[2][2][4];
#pragma unroll
    for (int ni = 0; ni < 2; ++ni) {
      ushort4 fgu = *(const ushort4*)&fgl[it * 32 + ni * 16 + hi * 4];
      float fg0 = bf2f(fgu.x), fg1 = bf2f(fgu.y), fg2 = bf2f(fgu.z), fg3 = bf2f(fgu.w);
#pragma unroll
      for (int s = 0; s < 2; ++s) {
        float e0 = exp2f(sv[s][ni][0]);
        float e1 = exp2f(sv[s][ni][1]);
        float e2 = exp2f(sv[s][ni][2]);
        float e3 = exp2f(sv[s][ni][3]);
        lsum[s] += e0 * fg0 + e1 * fg1 + e2 * fg2 + e3 * fg3;
        p0[s][ni][0] = e0; p0[s][ni][1] = e1; p0[s][ni][2] = e2; p0[s][ni][3] = e3;
      }
    }
    // P^T -> PV B-fragment in registers
    bf16x8 pbf[2];
#pragma unroll
    for (int s = 0; s < 2; ++s) {
      unsigned int pk00, pk01, pk10, pk11;
      asm("v_cvt_pk_bf16_f32 %0, %1, %2" : "=v"(pk00) : "v"(p0[s][0][0]), "v"(p0[s][0][1]));
      asm("v_cvt_pk_bf16_f32 %0, %1, %2" : "=v"(pk01) : "v"(p0[s][0][2]), "v"(p0[s][0][3]));
      asm("v_cvt_pk_bf16_f32 %0, %1, %2" : "=v"(pk10) : "v"(p0[s][1][0]), "v"(p0[s][1][1]));
      asm("v_cvt_pk_bf16_f32 %0, %1, %2" : "=v"(pk11) : "v"(p0[s][1][2]), "v"(p0[s][1][3]));
      int a00 = __shfl((int)pk00, srcA); int a10 = __shfl((int)pk10, srcA);
      int a01 = __shfl((int)pk01, srcA); int a11 = __shfl((int)pk11, srcA);
      int b00 = __shfl((int)pk00, srcB); int b10 = __shfl((int)pk10, srcB);
      int b01 = __shfl((int)pk01, srcB); int b11 = __shfl((int)pk11, srcB);
      u32x4 tv;
      tv.x = (unsigned)(hi < 2 ? a00 : a10);
      tv.y = (unsigned)(hi < 2 ? a01 : a11);
      tv.z = (unsigned)(hi < 2 ? b00 : b10);
      tv.w = (unsigned)(hi < 2 ? b01 : b11);
      pbf[s] = __builtin_bit_cast(bf16x8, tv);
    }
    // PV^T: A = V^T-frag, B = P^T
    __builtin_amdgcn_s_setprio(1);
#pragma unroll
    for (int cf = 0; cf < 16; ++cf) {
      int row = cf * 16 + lo;
      const char* vp = (const char*)&Vl[cur][0] + row * 64 + ((hi ^ (lo & 3) ^ ((lo >> 2) & 3)) << 4);
      bf16x8 vb = *(const bf16x8*)vp;
#pragma unroll
      for (int s = 0; s < 2; ++s)
        acc[s][cf] = __builtin_amdgcn_mfma_f32_16x16x32_bf16(vb, pbf[s], acc[s][cf], 0, 0, 0);
    }
    __builtin_amdgcn_s_setprio(0);
    __syncthreads();   // drains next-tile stage loads + all waves done with buf[cur]
  }
  // l reduction over the 4 hi-groups (lanes differing in bits 4,5 share q=lo)
  float ls[2];
#pragma unroll
  for (int s = 0; s < 2; ++s) {
    float t = lsum[s];
    t += __shfl_xor(t, 16);
    t += __shfl_xor(t, 32);
    ls[s] = t;
  }
  // epilogue: bf16 unnormalized partials + (FM, l); split 7 lands in the xbf region
  const size_t RN = (size_t)BATCH * NTOK;
  u16* pbase = (s_k < 7) ? (pacc + (size_t)s_k * RN * CDIM) : pacc7;
  u16* pb = pbase + ((size_t)b * NTOK + n0) * CDIM;
  float2* pm = pml + (size_t)s_k * RN + (size_t)b * NTOK + n0;
#pragma unroll
  for (int s = 0; s < 2; ++s) {
#pragma unroll
    for (int cf = 0; cf < 16; ++cf) {
      ushort4 st;
      st.x = f2bf(acc[s][cf][0]);
      st.y = f2bf(acc[s][cf][1]);
      st.z = f2bf(acc[s][cf][2]);
      st.w = f2bf(acc[s][cf][3]);
      *(ushort4*)&pb[(size_t)(s * 16 + lo) * CDIM + cf * 16 + hi * 4] = st;
    }
    if (lane < 16) {
      float2 v; v.x = FM; v.y = ls[s];
      pm[s * 16 + lane] = v;
    }
  }
}

// ---------------- K5: fused combine(8 splits) + projection ----------------
__global__ __launch_bounds__(256) void k_proj(const u16* __restrict__ pacc, const u16* __restrict__ pacc7,
                                              const float2* __restrict__ pml,
                                              const u16* __restrict__ wp,
                                              const float* __restrict__ bproj, float* __restrict__ out) {
  __shared__ u16 Al[128][72];
  __shared__ u16 Bl[128][72];
  __shared__ float invl[128];
  const size_t RN = (size_t)BATCH * NTOK;
  int n0 = blockIdx.x * 128;
  int c0 = blockIdx.y * 128;
  int b  = blockIdx.z;
  int tid = threadIdx.x;
  int lane = tid & 63, w = tid >> 6;
  int lo = lane & 15, hi = lane >> 4;
  int wm = w >> 1, wn = w & 1;
  if (tid < 128) {
    float d = 0.0f;
#pragma unroll
    for (int s = 0; s < 8; ++s)
      d += pml[(size_t)s * RN + (size_t)b * NTOK + n0 + tid].y;
    invl[tid] = 1.0f / d;
  }
  f32x4 acc[4][4] = {};
  const u16* Ab = wp + (size_t)c0 * CDIM;
  for (int kcs = 0; kcs < 256; kcs += 64) {
    __syncthreads();
#pragma unroll
    for (int i = 0; i < 4; ++i) {
      int cid = i * 256 + tid;
      int row = cid >> 3, cc = cid & 7;
      *(uint4*)&Al[row][cc * 8] = *(const uint4*)(Ab + (size_t)row * CDIM + kcs + cc * 8);
      // B: sum 8 bf16 splits of pacc, scale by 1/l, back to bf16
      size_t off = ((size_t)b * NTOK + n0 + row) * CDIM + kcs + cc * 8;
      float v[8] = {0, 0, 0, 0, 0, 0, 0, 0};
#pragma unroll
      for (int s = 0; s < 8; ++s) {
        const u16* sp = (s < 7) ? (pacc + (size_t)s * RN * CDIM) : pacc7;
        uint4 u = *(const uint4*)(sp + off);
        const u16* pu = (const u16*)&u;
#pragma unroll
        for (int j = 0; j < 8; ++j) v[j] += bf2f(pu[j]);
      }
      float iv = invl[row];
      ushort4 o0, o1;
      o0.x = f2bf(v[0] * iv); o0.y = f2bf(v[1] * iv); o0.z = f2bf(v[2] * iv); o0.w = f2bf(v[3] * iv);
      o1.x = f2bf(v[4] * iv); o1.y = f2bf(v[5] * iv); o1.z = f2bf(v[6] * iv); o1.w = f2bf(v[7] * iv);
      *(ushort4*)&Bl[row][cc * 8]     = o0;
      *(ushort4*)&Bl[row][cc * 8 + 4] = o1;
    }
    __syncthreads();
#pragma unroll
    for (int kk = 0; kk < 2; ++kk) {
      bf16x8 af[4], bfr[4];
#pragma unroll
      for (int mi = 0; mi < 4; ++mi) af[mi]  = *(const bf16x8*)&Al[wm * 64 + mi * 16 + lo][kk * 32 + hi * 8];
#pragma unroll
      for (int ni = 0; ni < 4; ++ni) bfr[ni] = *(const bf16x8*)&Bl[wn * 64 + ni * 16 + lo][kk * 32 + hi * 8];
#pragma unroll
      for (int mi = 0; mi < 4; ++mi)
#pragma unroll
        for (int ni = 0; ni < 4; ++ni)
          acc[mi][ni] = __builtin_amdgcn_mfma_f32_16x16x32_bf16(af[mi], bfr[ni], acc[mi][ni], 0, 0, 0);
    }
  }
#pragma unroll
  for (int mi = 0; mi < 4; ++mi) {
    int cbase = c0 + wm * 64 + mi * 16 + hi * 4;
#pragma unroll
    for (int r = 0; r < 4; ++r) {
      float bias = bproj[cbase + r];
#pragma unroll
      for (int ni = 0; ni < 4; ++ni) {
        int n = n0 + wn * 64 + ni * 16 + lo;
        out[((size_t)b * CDIM + cbase + r) * NTOK + n] = acc[mi][ni][r] + bias;
      }
    }
  }
}

extern "C" void kernel_launch(void* const* d_in, const int* in_sizes, int n_in,
                              void* d_out, int out_size, void* d_ws, size_t ws_size,
                              hipStream_t stream) {
  const float* x     = (const float*)d_in[0];
  const int*   fg    = (const int*)d_in[1];
  const float* Wqkv  = (const float*)d_in[2];
  const float* Wproj = (const float*)d_in[3];
  const float* bproj = (const float*)d_in[4];
  float* out = (float*)d_out;
  char* ws = (char*)d_ws;
  u16*   xbf  = (u16*)(ws);                    // 8388608 B (reused as pacc split 7)
  u8*    Qm8  = (u8*)(ws + 8388608);           // 4194304
  u8*    Km8  = (u8*)(ws + 12582912);          // 4194304
  u16*   Vt   = (u16*)(ws + 16777216);         // 272*4096*2*4 = 8912896
  u16*   wq   = (u16*)(ws + 25690112);         // 393216
  u16*   wp   = (u16*)(ws + 26083328);         // 131072  -> ends 26214400
  u16*   pacc = (u16*)(ws + 26214400);         // 7 x 8 MiB bf16 = 58720256 -> ends 84934656
  float2* pml = (float2*)(ws + 84934656);      // 8*16384*8 = 1 MiB -> ends 85983232
  u16*   pacc7 = xbf;

  k_prep<<<1088, 256, 0, stream>>>(Wqkv, Wproj, fg, wq, wp, Vt);
  k_transpose<<<dim3(64, 4, 4), 256, 0, stream>>>(x, xbf);
  k_qkv<<<dim3(32, 6, 4), 256, 0, stream>>>(xbf, wq, fg, Qm8, Km8, Vt);
  k_attn<<<1024, 256, 0, stream>>>(Qm8, Km8, Vt, pacc, pacc7, pml);
  k_proj<<<dim3(32, 2, 4), 256, 0, stream>>>(pacc, pacc7, pml, wp, bproj, out);
}

// Round 15
// 146.301 us; speedup vs baseline: 2.2105x; 2.2105x over previous
//
#include <hip/hip_runtime.h>
#include <hip/hip_bf16.h>

#define BATCH 4
#define CDIM  256
#define NTOK  4096
#define THREE (3*CDIM)
#define VROWS 272   // 256 V channels + fg row at 256 (257..271 unused)

typedef unsigned short u16;
typedef unsigned char u8;
typedef long i64;
typedef __attribute__((ext_vector_type(4))) float f32x4;
typedef __attribute__((ext_vector_type(8))) short bf16x8;
typedef __attribute__((ext_vector_type(4))) unsigned int u32x4;

#define AS1 __attribute__((address_space(1)))
#define AS3 __attribute__((address_space(3)))

__device__ __forceinline__ u16 f2bf(float x) {
  unsigned int u = __float_as_uint(x);
  unsigned int r = (u + 0x7fffu + ((u >> 16) & 1u)) >> 16;   // RTNE
  return (u16)r;
}
__device__ __forceinline__ float bf2f(u16 v) {
  return __uint_as_float(((unsigned int)v) << 16);
}
__device__ __forceinline__ u8 f2fp8(float x) {
  int r = __builtin_amdgcn_cvt_pk_fp8_f32(x, 0.0f, 0, false);  // e4m3 (OCP), RNE
  return (u8)(r & 0xff);
}
__device__ __forceinline__ void gload_lds16(const void* g, void* l) {
  __builtin_amdgcn_global_load_lds((AS1 const void*)g, (AS3 void*)l, 16, 0, 0);
}

// both Q and K carry sqrt(log2e/16) so (Q'.K') is directly in log2 domain
#define SC8 0.30028132f

// ---------------- K1: weights -> bf16; fg -> bf16 row in Vt ----------------
__global__ void k_prep(const float* __restrict__ Wqkv, const float* __restrict__ Wproj,
                       const int* __restrict__ fg,
                       u16* __restrict__ wq, u16* __restrict__ wp,
                       u16* __restrict__ Vt) {
  int i = blockIdx.x * 256 + threadIdx.x;
  const int nq = THREE * CDIM;          // 196608
  const int np = CDIM * CDIM;           // 65536
  const int nf = BATCH * NTOK;          // 16384 (fg row c=256)
  if (i < nq) { wq[i] = f2bf(Wqkv[i]); return; }
  int j = i - nq;
  if (j < np) { wp[j] = f2bf(Wproj[j]); return; }
  int k = j - np;
  if (k < nf) {
    int b = k >> 12, key = k & (NTOK - 1);
    Vt[((size_t)b * VROWS + 256) * NTOK + key] = fg[k] ? 0x3F80 : 0;  // bf16 1.0/0.0
  }
}

// ---------------- K2: x [B][C][N] f32 -> xbf [B][N][C] bf16 ----------------
__global__ __launch_bounds__(256) void k_transpose(const float* __restrict__ x, u16* __restrict__ xbf) {
  __shared__ u16 t[64][65];
  int n0 = blockIdx.x * 64;
  int c0 = blockIdx.y * 64;
  int b  = blockIdx.z;
  int tid = threadIdx.x;
  const float* xp = x + (size_t)b * CDIM * NTOK;
  int nl = tid & 63;
  int cb = tid >> 6;
#pragma unroll
  for (int i = 0; i < 16; ++i) {
    int cl = cb * 16 + i;
    t[nl][cl] = f2bf(xp[(size_t)(c0 + cl) * NTOK + n0 + nl]);
  }
  __syncthreads();
  int cl = tid & 63;
  int nb = tid >> 6;
  u16* op = xbf + ((size_t)b * NTOK + n0) * CDIM + c0;
#pragma unroll
  for (int i = 0; i < 16; ++i) {
    int nl2 = nb * 16 + i;
    op[(size_t)nl2 * CDIM + cl] = t[nl2][cl];
  }
}

// ---------------- K3: qkv GEMM. Q,K -> fp8 e4m3 (x SC8 each); V^T [c][key] bf16, fg-zeroed ----------------
__global__ __launch_bounds__(256) void k_qkv(const u16* __restrict__ xbf, const u16* __restrict__ wq,
                                             const int* __restrict__ fg,
                                             u8* __restrict__ Qm8, u8* __restrict__ Km8,
                                             u16* __restrict__ Vt) {
  __shared__ u16 Al[128][72];
  __shared__ u16 Bl[128][72];
  int n0 = blockIdx.x * 128;
  int d0 = blockIdx.y * 128;
  int b  = blockIdx.z;
  int tid = threadIdx.x;
  int lane = tid & 63, w = tid >> 6;
  int lo = lane & 15, hi = lane >> 4;
  int wm = w >> 1, wn = w & 1;
  f32x4 acc[4][4] = {};
  const u16* Ab = xbf + ((size_t)b * NTOK + n0) * CDIM;
  const u16* Bb = wq + (size_t)d0 * CDIM;
  for (int kc = 0; kc < 256; kc += 64) {
    __syncthreads();
#pragma unroll
    for (int i = 0; i < 4; ++i) {
      int cid = i * 256 + tid;
      int row = cid >> 3, cc = cid & 7;
      *(uint4*)&Al[row][cc * 8] = *(const uint4*)(Ab + (size_t)row * CDIM + kc + cc * 8);
      *(uint4*)&Bl[row][cc * 8] = *(const uint4*)(Bb + (size_t)row * CDIM + kc + cc * 8);
    }
    __syncthreads();
#pragma unroll
    for (int kk = 0; kk < 2; ++kk) {
      bf16x8 af[4], bfr[4];
#pragma unroll
      for (int mi = 0; mi < 4; ++mi) af[mi]  = *(const bf16x8*)&Al[wm * 64 + mi * 16 + lo][kk * 32 + hi * 8];
#pragma unroll
      for (int ni = 0; ni < 4; ++ni) bfr[ni] = *(const bf16x8*)&Bl[wn * 64 + ni * 16 + lo][kk * 32 + hi * 8];
#pragma unroll
      for (int mi = 0; mi < 4; ++mi)
#pragma unroll
        for (int ni = 0; ni < 4; ++ni)
          acc[mi][ni] = __builtin_amdgcn_mfma_f32_16x16x32_bf16(af[mi], bfr[ni], acc[mi][ni], 0, 0, 0);
    }
  }
  int seg = d0 >> 8;   // 0=Q 1=K 2=V
#pragma unroll
  for (int mi = 0; mi < 4; ++mi) {
    int nbase = n0 + wm * 64 + mi * 16 + hi * 4;
#pragma unroll
    for (int ni = 0; ni < 4; ++ni) {
      int d = d0 + wn * 64 + ni * 16 + lo;
      if (seg == 0) {
#pragma unroll
        for (int r = 0; r < 4; ++r)
          Qm8[((size_t)b * NTOK + nbase + r) * CDIM + d] = f2fp8(acc[mi][ni][r] * SC8);
      } else if (seg == 1) {
        int dk = d - 256;
#pragma unroll
        for (int r = 0; r < 4; ++r)
          Km8[((size_t)b * NTOK + nbase + r) * CDIM + dk] = f2fp8(acc[mi][ni][r] * SC8);
      } else {
        int dv = d - 512;
        ushort4 pk;
        pk.x = fg[b * NTOK + nbase + 0] ? f2bf(acc[mi][ni][0]) : (u16)0;
        pk.y = fg[b * NTOK + nbase + 1] ? f2bf(acc[mi][ni][1]) : (u16)0;
        pk.z = fg[b * NTOK + nbase + 2] ? f2bf(acc[mi][ni][2]) : (u16)0;
        pk.w = fg[b * NTOK + nbase + 3] ? f2bf(acc[mi][ni][3]) : (u16)0;
        *(ushort4*)&Vt[((size_t)b * VROWS + dv) * NTOK + nbase] = pk;
      }
    }
  }
}

// ---------------- K4: flash attention, fp8 QK, R13 schedule (split-4, 2 blocks/CU) ----------------
// grid = 512 blocks; 4 waves x 32 q-rows; KBLK=32; double-buffered staging; LDS 50KB.
// S^T = mfma_fp8(K',Q') directly in log2 domain; P^T in registers (cvt_pk+shfl);
// PV^T = mfma(V^T, P^T) bf16. Fixed max FM=12; mask via zeroed V rows; l = sum P*fg.
__global__ __launch_bounds__(256, 2) void k_attn(const u8* __restrict__ Qm8, const u8* __restrict__ Km8,
                                                 const u16* __restrict__ Vt,
                                                 u16* __restrict__ pacc, float2* __restrict__ pml,
                                                 int lsplit) {
  __shared__ u8  Kl[2][32 * 256];    // 8KB x2 fp8; 16B-chunk ^= (row&7)
  __shared__ u16 Vl[2][256 * 32];    // 16KB x2 bf16; chunk ^= (row&3)^((row>>2)&3)
  __shared__ u16 fgl[1024];          // bf16 fg for this chunk's 1024 keys
  const float FM = 12.0f;
  int nwg = gridDim.x;
  int cpx = nwg >> 3;
  int orig = blockIdx.x;
  int wg = (orig & 7) * cpx + (orig >> 3);   // bijective XCD swizzle (nwg % 8 == 0)
  int qt = wg & 31;
  int bs = wg >> 5;
  int s_k = bs & ((1 << lsplit) - 1);
  int b   = bs >> lsplit;
  int chunk = NTOK >> lsplit;                // 1024
  int koff  = s_k * chunk;
  int iters = chunk >> 5;                    // 32

  int tid = threadIdx.x;
  int lane = tid & 63, w = tid >> 6;
  int lo = lane & 15, hi = lane >> 4;
  int n0 = qt * 128 + w * 32;
  // Q': 32 rows x 256 fp8 in registers (16 VGPR)
  i64 qf[2][8];
#pragma unroll
  for (int s = 0; s < 2; ++s) {
    const u8* qp = Qm8 + ((size_t)b * NTOK + n0 + s * 16 + lo) * CDIM + hi * 8;
#pragma unroll
    for (int ks = 0; ks < 8; ++ks) qf[s][ks] = *(const i64*)(qp + ks * 32);
  }
  f32x4 acc[2][16] = {};   // out^T: acc[s][cf][r] = out[d=cf*16+hi*4+r][q=s*16+lo]
  float lsum[2] = {0.0f, 0.0f};
  const u8*  kbase = Km8 + (size_t)b * NTOK * CDIM;
  const u16* vbase = Vt + (size_t)b * VROWS * NTOK;
  const u16* fgrow = vbase + (size_t)256 * NTOK;   // bf16 fg row
  int vr  = lane >> 2;   // V staging: row within 16-row group
  int vc  = lane & 3;
  int srcA = lo + ((hi & 1) << 5);   // P^T exchange source lanes
  int srcB = srcA + 16;

  // stage K (2 insts/wave, fp8) and V (4 insts/wave) for key-block m0 into buffer buf
  auto stage = [&](int buf, int m0) {
#pragma unroll
    for (int j = 0; j < 2; ++j) {
      int rl = w * 8 + j * 4 + (lane >> 4);          // row within 32-row tile
      int sb = ((lane & 15) << 4) ^ ((rl & 7) << 4); // source pre-swizzle (16B chunks)
      gload_lds16(kbase + (size_t)(m0 + rl) * CDIM + sb,
                  &Kl[buf][w * 2048 + j * 1024]);
    }
#pragma unroll
    for (int j = 0; j < 4; ++j) {
      int idx = j * 4 + w;                 // 0..15
      int r = idx * 16 + vr;
      int d = vc ^ (r & 3) ^ ((r >> 2) & 3);
      gload_lds16(vbase + (size_t)r * NTOK + m0 + d * 8, &Vl[buf][idx * 512]);
    }
  };

  // prologue: fg chunk (waves 0,1: dest base is lane0's ptr + lane*16B) + tile 0
  if (w < 2) gload_lds16(fgrow + koff + w * 512 + lane * 8, &fgl[w * 512 + lane * 8]);
  stage(0, koff);
  __syncthreads();
  for (int it = 0; it < iters; ++it) {
    int cur = it & 1;
    int m0 = koff + it * 32;
    if (it + 1 < iters) stage(cur ^ 1, m0 + 32);   // prefetch next tile
    // S^T - FM: A = K' (fp8), B = Q' (fp8), scales pre-folded to log2 domain
    f32x4 sv[2][2];
#pragma unroll
    for (int s = 0; s < 2; ++s)
#pragma unroll
      for (int ni = 0; ni < 2; ++ni)
#pragma unroll
        for (int r = 0; r < 4; ++r) sv[s][ni][r] = -FM;
    __builtin_amdgcn_s_setprio(1);
#pragma unroll
    for (int ks = 0; ks < 8; ++ks) {
      i64 kf[2];
#pragma unroll
      for (int ni = 0; ni < 2; ++ni) {
        int row = ni * 16 + lo;
        int byteoff = row * 256 + ((((ks * 2 + (hi >> 1)) << 4) ^ ((row & 7) << 4))) + ((hi & 1) << 3);
        kf[ni] = *(const i64*)((const char*)&Kl[cur][0] + byteoff);
      }
#pragma unroll
      for (int s = 0; s < 2; ++s)
#pragma unroll
        for (int ni = 0; ni < 2; ++ni)
          sv[s][ni] = __builtin_amdgcn_mfma_f32_16x16x32_fp8_fp8(kf[ni], qf[s][ks], sv[s][ni], 0, 0, 0);
    }
    __builtin_amdgcn_s_setprio(0);
    // P = exp2(S^T - FM); lane covers keys {ni*16 + hi*4 + r} for q = s*16+lo.
    float p0[2][2][4];
#pragma unroll
    for (int ni = 0; ni < 2; ++ni) {
      ushort4 fgu = *(const ushort4*)&fgl[it * 32 + ni * 16 + hi * 4];
      float fg0 = bf2f(fgu.x), fg1 = bf2f(fgu.y), fg2 = bf2f(fgu.z), fg3 = bf2f(fgu.w);
#pragma unroll
      for (int s = 0; s < 2; ++s) {
        float e0 = exp2f(sv[s][ni][0]);
        float e1 = exp2f(sv[s][ni][1]);
        float e2 = exp2f(sv[s][ni][2]);
        float e3 = exp2f(sv[s][ni][3]);
        lsum[s] += e0 * fg0 + e1 * fg1 + e2 * fg2 + e3 * fg3;
        p0[s][ni][0] = e0; p0[s][ni][1] = e1; p0[s][ni][2] = e2; p0[s][ni][3] = e3;
      }
    }
    // P^T -> PV B-fragment in registers
    bf16x8 pbf[2];
#pragma unroll
    for (int s = 0; s < 2; ++s) {
      unsigned int pk00, pk01, pk10, pk11;
      asm("v_cvt_pk_bf16_f32 %0, %1, %2" : "=v"(pk00) : "v"(p0[s][0][0]), "v"(p0[s][0][1]));
      asm("v_cvt_pk_bf16_f32 %0, %1, %2" : "=v"(pk01) : "v"(p0[s][0][2]), "v"(p0[s][0][3]));
      asm("v_cvt_pk_bf16_f32 %0, %1, %2" : "=v"(pk10) : "v"(p0[s][1][0]), "v"(p0[s][1][1]));
      asm("v_cvt_pk_bf16_f32 %0, %1, %2" : "=v"(pk11) : "v"(p0[s][1][2]), "v"(p0[s][1][3]));
      int a00 = __shfl((int)pk00, srcA); int a10 = __shfl((int)pk10, srcA);
      int a01 = __shfl((int)pk01, srcA); int a11 = __shfl((int)pk11, srcA);
      int b00 = __shfl((int)pk00, srcB); int b10 = __shfl((int)pk10, srcB);
      int b01 = __shfl((int)pk01, srcB); int b11 = __shfl((int)pk11, srcB);
      u32x4 tv;
      tv.x = (unsigned)(hi < 2 ? a00 : a10);
      tv.y = (unsigned)(hi < 2 ? a01 : a11);
      tv.z = (unsigned)(hi < 2 ? b00 : b10);
      tv.w = (unsigned)(hi < 2 ? b01 : b11);
      pbf[s] = __builtin_bit_cast(bf16x8, tv);
    }
    // PV^T: A = V^T-frag, B = P^T
    __builtin_amdgcn_s_setprio(1);
#pragma unroll
    for (int cf = 0; cf < 16; ++cf) {
      int row = cf * 16 + lo;
      const char* vp = (const char*)&Vl[cur][0] + row * 64 + ((hi ^ (lo & 3) ^ ((lo >> 2) & 3)) << 4);
      bf16x8 vb = *(const bf16x8*)vp;
#pragma unroll
      for (int s = 0; s < 2; ++s)
        acc[s][cf] = __builtin_amdgcn_mfma_f32_16x16x32_bf16(vb, pbf[s], acc[s][cf], 0, 0, 0);
    }
    __builtin_amdgcn_s_setprio(0);
    __syncthreads();   // drains next-tile stage loads + all waves done with buf[cur]
  }
  // l reduction over the 4 hi-groups (lanes differing in bits 4,5 share q=lo)
  float ls[2];
#pragma unroll
  for (int s = 0; s < 2; ++s) {
    float t = lsum[s];
    t += __shfl_xor(t, 16);
    t += __shfl_xor(t, 32);
    ls[s] = t;
  }
  // epilogue: bf16 unnormalized partials (out^T regs -> row-major [q][d] stores) + (FM, l)
  u16* pb = pacc + (((size_t)s_k * BATCH + b) * NTOK + n0) * CDIM;
  float2* pm = pml + ((size_t)s_k * BATCH + b) * NTOK + n0;
#pragma unroll
  for (int s = 0; s < 2; ++s) {
#pragma unroll
    for (int cf = 0; cf < 16; ++cf) {
      ushort4 st;
      st.x = f2bf(acc[s][cf][0]);
      st.y = f2bf(acc[s][cf][1]);
      st.z = f2bf(acc[s][cf][2]);
      st.w = f2bf(acc[s][cf][3]);
      *(ushort4*)&pb[(size_t)(s * 16 + lo) * CDIM + cf * 16 + hi * 4] = st;
    }
    if (lane < 16) {
      float2 v; v.x = FM; v.y = ls[s];
      pm[s * 16 + lane] = v;
    }
  }
}

// ---------------- K5: fused combine(4 splits) + projection ----------------
__global__ __launch_bounds__(256) void k_proj(const u16* __restrict__ pacc,
                                              const float2* __restrict__ pml,
                                              const u16* __restrict__ wp,
                                              const float* __restrict__ bproj, float* __restrict__ out) {
  __shared__ u16 Al[128][72];
  __shared__ u16 Bl[128][72];
  __shared__ float invl[128];
  const size_t RN = (size_t)BATCH * NTOK;
  int n0 = blockIdx.x * 128;
  int c0 = blockIdx.y * 128;
  int b  = blockIdx.z;
  int tid = threadIdx.x;
  int lane = tid & 63, w = tid >> 6;
  int lo = lane & 15, hi = lane >> 4;
  int wm = w >> 1, wn = w & 1;
  if (tid < 128) {
    float d = 0.0f;
#pragma unroll
    for (int s = 0; s < 4; ++s)
      d += pml[(size_t)s * RN + (size_t)b * NTOK + n0 + tid].y;
    invl[tid] = 1.0f / d;
  }
  f32x4 acc[4][4] = {};
  const u16* Ab = wp + (size_t)c0 * CDIM;
  for (int kcs = 0; kcs < 256; kcs += 64) {
    __syncthreads();
#pragma unroll
    for (int i = 0; i < 4; ++i) {
      int cid = i * 256 + tid;
      int row = cid >> 3, cc = cid & 7;
      *(uint4*)&Al[row][cc * 8] = *(const uint4*)(Ab + (size_t)row * CDIM + kcs + cc * 8);
      // B: sum 4 bf16 splits of pacc, scale by 1/l, back to bf16
      size_t off = ((size_t)b * NTOK + n0 + row) * CDIM + kcs + cc * 8;
      float v[8] = {0, 0, 0, 0, 0, 0, 0, 0};
#pragma unroll
      for (int s = 0; s < 4; ++s) {
        uint4 u = *(const uint4*)(pacc + (size_t)s * RN * CDIM + off);
        const u16* pu = (const u16*)&u;
#pragma unroll
        for (int j = 0; j < 8; ++j) v[j] += bf2f(pu[j]);
      }
      float iv = invl[row];
      ushort4 o0, o1;
      o0.x = f2bf(v[0] * iv); o0.y = f2bf(v[1] * iv); o0.z = f2bf(v[2] * iv); o0.w = f2bf(v[3] * iv);
      o1.x = f2bf(v[4] * iv); o1.y = f2bf(v[5] * iv); o1.z = f2bf(v[6] * iv); o1.w = f2bf(v[7] * iv);
      *(ushort4*)&Bl[row][cc * 8]     = o0;
      *(ushort4*)&Bl[row][cc * 8 + 4] = o1;
    }
    __syncthreads();
#pragma unroll
    for (int kk = 0; kk < 2; ++kk) {
      bf16x8 af[4], bfr[4];
#pragma unroll
      for (int mi = 0; mi < 4; ++mi) af[mi]  = *(const bf16x8*)&Al[wm * 64 + mi * 16 + lo][kk * 32 + hi * 8];
#pragma unroll
      for (int ni = 0; ni < 4; ++ni) bfr[ni] = *(const bf16x8*)&Bl[wn * 64 + ni * 16 + lo][kk * 32 + hi * 8];
#pragma unroll
      for (int mi = 0; mi < 4; ++mi)
#pragma unroll
        for (int ni = 0; ni < 4; ++ni)
          acc[mi][ni] = __builtin_amdgcn_mfma_f32_16x16x32_bf16(af[mi], bfr[ni], acc[mi][ni], 0, 0, 0);
    }
  }
#pragma unroll
  for (int mi = 0; mi < 4; ++mi) {
    int cbase = c0 + wm * 64 + mi * 16 + hi * 4;
#pragma unroll
    for (int r = 0; r < 4; ++r) {
      float bias = bproj[cbase + r];
#pragma unroll
      for (int ni = 0; ni < 4; ++ni) {
        int n = n0 + wn * 64 + ni * 16 + lo;
        out[((size_t)b * CDIM + cbase + r) * NTOK + n] = acc[mi][ni][r] + bias;
      }
    }
  }
}

extern "C" void kernel_launch(void* const* d_in, const int* in_sizes, int n_in,
                              void* d_out, int out_size, void* d_ws, size_t ws_size,
                              hipStream_t stream) {
  const float* x     = (const float*)d_in[0];
  const int*   fg    = (const int*)d_in[1];
  const float* Wqkv  = (const float*)d_in[2];
  const float* Wproj = (const float*)d_in[3];
  const float* bproj = (const float*)d_in[4];
  float* out = (float*)d_out;
  char* ws = (char*)d_ws;
  u16*   xbf  = (u16*)(ws);                    // 8388608 B
  u8*    Qm8  = (u8*)(ws + 8388608);           // 4194304
  u8*    Km8  = (u8*)(ws + 12582912);          // 4194304
  u16*   Vt   = (u16*)(ws + 16777216);         // 272*4096*2*4 = 8912896
  u16*   wq   = (u16*)(ws + 25690112);         // 393216
  u16*   wp   = (u16*)(ws + 26083328);         // 131072  -> ends 26214400
  u16*   pacc = (u16*)(ws + 26214400);         // 4 x 8 MiB bf16 = 33554432 -> ends 59768832
  float2* pml = (float2*)(ws + 59768832);      // 512 KiB -> ends 60293120

  k_prep<<<1088, 256, 0, stream>>>(Wqkv, Wproj, fg, wq, wp, Vt);
  k_transpose<<<dim3(64, 4, 4), 256, 0, stream>>>(x, xbf);
  k_qkv<<<dim3(32, 6, 4), 256, 0, stream>>>(xbf, wq, fg, Qm8, Km8, Vt);
  k_attn<<<512, 256, 0, stream>>>(Qm8, Km8, Vt, pacc, pml, 2);
  k_proj<<<dim3(32, 2, 4), 256, 0, stream>>>(pacc, pml, wp, bproj, out);
}

// Round 16
// 138.743 us; speedup vs baseline: 2.3309x; 1.0545x over previous
//
#include <hip/hip_runtime.h>
#include <hip/hip_bf16.h>

#define BATCH 4
#define CDIM  256
#define NTOK  4096
#define THREE (3*CDIM)
#define VROWS 272   // 256 V channels + fg row at 256 (257..271 unused)

typedef unsigned short u16;
typedef unsigned char u8;
typedef long i64;
typedef __attribute__((ext_vector_type(4))) float f32x4;
typedef __attribute__((ext_vector_type(8))) short bf16x8;
typedef __attribute__((ext_vector_type(4))) unsigned int u32x4;

#define AS1 __attribute__((address_space(1)))
#define AS3 __attribute__((address_space(3)))

__device__ __forceinline__ u16 f2bf(float x) {
  unsigned int u = __float_as_uint(x);
  unsigned int r = (u + 0x7fffu + ((u >> 16) & 1u)) >> 16;   // RTNE
  return (u16)r;
}
__device__ __forceinline__ float bf2f(u16 v) {
  return __uint_as_float(((unsigned int)v) << 16);
}
__device__ __forceinline__ u8 f2fp8(float x) {
  int r = __builtin_amdgcn_cvt_pk_fp8_f32(x, 0.0f, 0, false);  // e4m3 (OCP), RNE
  return (u8)(r & 0xff);
}
__device__ __forceinline__ void gload_lds16(const void* g, void* l) {
  __builtin_amdgcn_global_load_lds((AS1 const void*)g, (AS3 void*)l, 16, 0, 0);
}

// both Q and K carry sqrt(log2e/16) so (Q'.K') is directly in log2 domain
#define SC8 0.30028132f

// ---------------- K1: weights -> bf16; fg -> bf16 row in Vt ----------------
__global__ void k_prep(const float* __restrict__ Wqkv, const float* __restrict__ Wproj,
                       const int* __restrict__ fg,
                       u16* __restrict__ wq, u16* __restrict__ wp,
                       u16* __restrict__ Vt) {
  int i = blockIdx.x * 256 + threadIdx.x;
  const int nq = THREE * CDIM;          // 196608
  const int np = CDIM * CDIM;           // 65536
  const int nf = BATCH * NTOK;          // 16384 (fg row c=256)
  if (i < nq) { wq[i] = f2bf(Wqkv[i]); return; }
  int j = i - nq;
  if (j < np) { wp[j] = f2bf(Wproj[j]); return; }
  int k = j - np;
  if (k < nf) {
    int b = k >> 12, key = k & (NTOK - 1);
    Vt[((size_t)b * VROWS + 256) * NTOK + key] = fg[k] ? 0x3F80 : 0;  // bf16 1.0/0.0
  }
}

// ---------------- K2: x [B][C][N] f32 -> xbf [B][N][C] bf16 ----------------
__global__ __launch_bounds__(256) void k_transpose(const float* __restrict__ x, u16* __restrict__ xbf) {
  __shared__ u16 t[64][65];
  int n0 = blockIdx.x * 64;
  int c0 = blockIdx.y * 64;
  int b  = blockIdx.z;
  int tid = threadIdx.x;
  const float* xp = x + (size_t)b * CDIM * NTOK;
  int nl = tid & 63;
  int cb = tid >> 6;
#pragma unroll
  for (int i = 0; i < 16; ++i) {
    int cl = cb * 16 + i;
    t[nl][cl] = f2bf(xp[(size_t)(c0 + cl) * NTOK + n0 + nl]);
  }
  __syncthreads();
  int cl = tid & 63;
  int nb = tid >> 6;
  u16* op = xbf + ((size_t)b * NTOK + n0) * CDIM + c0;
#pragma unroll
  for (int i = 0; i < 16; ++i) {
    int nl2 = nb * 16 + i;
    op[(size_t)nl2 * CDIM + cl] = t[nl2][cl];
  }
}

// ---------------- K3: qkv GEMM (gload_lds staging). Q,K -> fp8 e4m3 (x SC8); V^T bf16, fg-zeroed ----------------
// A/B tiles staged via global_load_lds: linear LDS [128 rows x 128B], 16B chunk c
// holds global chunk c^(row&7); reads use the same XOR (2-way banks, free).
__global__ __launch_bounds__(256) void k_qkv(const u16* __restrict__ xbf, const u16* __restrict__ wq,
                                             const int* __restrict__ fg,
                                             u8* __restrict__ Qm8, u8* __restrict__ Km8,
                                             u16* __restrict__ Vt) {
  __shared__ u16 Al[128 * 64];   // 16KB
  __shared__ u16 Bl[128 * 64];   // 16KB
  int n0 = blockIdx.x * 128;
  int d0 = blockIdx.y * 128;
  int b  = blockIdx.z;
  int tid = threadIdx.x;
  int lane = tid & 63, w = tid >> 6;
  int lo = lane & 15, hi = lane >> 4;
  int wm = w >> 1, wn = w & 1;
  f32x4 acc[4][4] = {};
  const u16* Ab = xbf + ((size_t)b * NTOK + n0) * CDIM;
  const u16* Bb = wq + (size_t)d0 * CDIM;
  for (int kc = 0; kc < 256; kc += 64) {
    __syncthreads();
#pragma unroll
    for (int j = 0; j < 4; ++j) {
      int id = (j * 4 + w) * 64 + lane;     // 0..1023 16B-chunks
      int row = id >> 3, c = id & 7;
      int sc = c ^ (row & 7);               // source pre-swizzle
      gload_lds16(Ab + (size_t)row * CDIM + kc + sc * 8, &Al[(size_t)id * 8]);
      gload_lds16(Bb + (size_t)row * CDIM + kc + sc * 8, &Bl[(size_t)id * 8]);
    }
    __syncthreads();
#pragma unroll
    for (int kk = 0; kk < 2; ++kk) {
      bf16x8 af[4], bfr[4];
#pragma unroll
      for (int mi = 0; mi < 4; ++mi) {
        int row = wm * 64 + mi * 16 + lo;
        af[mi] = *(const bf16x8*)&Al[row * 64 + (((kk * 4 + hi) ^ (row & 7)) * 8)];
      }
#pragma unroll
      for (int ni = 0; ni < 4; ++ni) {
        int row = wn * 64 + ni * 16 + lo;
        bfr[ni] = *(const bf16x8*)&Bl[row * 64 + (((kk * 4 + hi) ^ (row & 7)) * 8)];
      }
#pragma unroll
      for (int mi = 0; mi < 4; ++mi)
#pragma unroll
        for (int ni = 0; ni < 4; ++ni)
          acc[mi][ni] = __builtin_amdgcn_mfma_f32_16x16x32_bf16(af[mi], bfr[ni], acc[mi][ni], 0, 0, 0);
    }
  }
  int seg = d0 >> 8;   // 0=Q 1=K 2=V
#pragma unroll
  for (int mi = 0; mi < 4; ++mi) {
    int nbase = n0 + wm * 64 + mi * 16 + hi * 4;
#pragma unroll
    for (int ni = 0; ni < 4; ++ni) {
      int d = d0 + wn * 64 + ni * 16 + lo;
      if (seg == 0) {
#pragma unroll
        for (int r = 0; r < 4; ++r)
          Qm8[((size_t)b * NTOK + nbase + r) * CDIM + d] = f2fp8(acc[mi][ni][r] * SC8);
      } else if (seg == 1) {
        int dk = d - 256;
#pragma unroll
        for (int r = 0; r < 4; ++r)
          Km8[((size_t)b * NTOK + nbase + r) * CDIM + dk] = f2fp8(acc[mi][ni][r] * SC8);
      } else {
        int dv = d - 512;
        ushort4 pk;
        pk.x = fg[b * NTOK + nbase + 0] ? f2bf(acc[mi][ni][0]) : (u16)0;
        pk.y = fg[b * NTOK + nbase + 1] ? f2bf(acc[mi][ni][1]) : (u16)0;
        pk.z = fg[b * NTOK + nbase + 2] ? f2bf(acc[mi][ni][2]) : (u16)0;
        pk.w = fg[b * NTOK + nbase + 3] ? f2bf(acc[mi][ni][3]) : (u16)0;
        *(ushort4*)&Vt[((size_t)b * VROWS + dv) * NTOK + nbase] = pk;
      }
    }
  }
}

// ---------------- K4: flash attention, fp8 QK, R13 schedule (split-4, 2 blocks/CU) ----------------
// grid = 512 blocks; 4 waves x 32 q-rows; KBLK=32; double-buffered staging; LDS 50KB.
// S^T = mfma_fp8(K',Q') directly in log2 domain; P^T in registers (cvt_pk+shfl);
// PV^T = mfma(V^T, P^T) bf16. Fixed max FM=12; mask via zeroed V rows; l = sum P*fg.
__global__ __launch_bounds__(256, 2) void k_attn(const u8* __restrict__ Qm8, const u8* __restrict__ Km8,
                                                 const u16* __restrict__ Vt,
                                                 u16* __restrict__ pacc, float2* __restrict__ pml,
                                                 int lsplit) {
  __shared__ u8  Kl[2][32 * 256];    // 8KB x2 fp8; 16B-chunk ^= (row&7)
  __shared__ u16 Vl[2][256 * 32];    // 16KB x2 bf16; chunk ^= (row&3)^((row>>2)&3)
  __shared__ u16 fgl[1024];          // bf16 fg for this chunk's 1024 keys
  const float FM = 12.0f;
  int nwg = gridDim.x;
  int cpx = nwg >> 3;
  int orig = blockIdx.x;
  int wg = (orig & 7) * cpx + (orig >> 3);   // bijective XCD swizzle (nwg % 8 == 0)
  int qt = wg & 31;
  int bs = wg >> 5;
  int s_k = bs & ((1 << lsplit) - 1);
  int b   = bs >> lsplit;
  int chunk = NTOK >> lsplit;                // 1024
  int koff  = s_k * chunk;
  int iters = chunk >> 5;                    // 32

  int tid = threadIdx.x;
  int lane = tid & 63, w = tid >> 6;
  int lo = lane & 15, hi = lane >> 4;
  int n0 = qt * 128 + w * 32;
  // Q': 32 rows x 256 fp8 in registers (16 VGPR)
  i64 qf[2][8];
#pragma unroll
  for (int s = 0; s < 2; ++s) {
    const u8* qp = Qm8 + ((size_t)b * NTOK + n0 + s * 16 + lo) * CDIM + hi * 8;
#pragma unroll
    for (int ks = 0; ks < 8; ++ks) qf[s][ks] = *(const i64*)(qp + ks * 32);
  }
  f32x4 acc[2][16] = {};   // out^T: acc[s][cf][r] = out[d=cf*16+hi*4+r][q=s*16+lo]
  float lsum[2] = {0.0f, 0.0f};
  const u8*  kbase = Km8 + (size_t)b * NTOK * CDIM;
  const u16* vbase = Vt + (size_t)b * VROWS * NTOK;
  const u16* fgrow = vbase + (size_t)256 * NTOK;   // bf16 fg row
  int vr  = lane >> 2;   // V staging: row within 16-row group
  int vc  = lane & 3;
  int srcA = lo + ((hi & 1) << 5);   // P^T exchange source lanes
  int srcB = srcA + 16;

  // stage K (2 insts/wave, fp8) and V (4 insts/wave) for key-block m0 into buffer buf
  auto stage = [&](int buf, int m0) {
#pragma unroll
    for (int j = 0; j < 2; ++j) {
      int rl = w * 8 + j * 4 + (lane >> 4);          // row within 32-row tile
      int sb = ((lane & 15) << 4) ^ ((rl & 7) << 4); // source pre-swizzle (16B chunks)
      gload_lds16(kbase + (size_t)(m0 + rl) * CDIM + sb,
                  &Kl[buf][w * 2048 + j * 1024]);
    }
#pragma unroll
    for (int j = 0; j < 4; ++j) {
      int idx = j * 4 + w;                 // 0..15
      int r = idx * 16 + vr;
      int d = vc ^ (r & 3) ^ ((r >> 2) & 3);
      gload_lds16(vbase + (size_t)r * NTOK + m0 + d * 8, &Vl[buf][idx * 512]);
    }
  };

  // prologue: fg chunk (waves 0,1: dest base is lane0's ptr + lane*16B) + tile 0
  if (w < 2) gload_lds16(fgrow + koff + w * 512 + lane * 8, &fgl[w * 512 + lane * 8]);
  stage(0, koff);
  __syncthreads();
  for (int it = 0; it < iters; ++it) {
    int cur = it & 1;
    int m0 = koff + it * 32;
    if (it + 1 < iters) stage(cur ^ 1, m0 + 32);   // prefetch next tile
    // S^T - FM: A = K' (fp8), B = Q' (fp8), scales pre-folded to log2 domain
    f32x4 sv[2][2];
#pragma unroll
    for (int s = 0; s < 2; ++s)
#pragma unroll
      for (int ni = 0; ni < 2; ++ni)
#pragma unroll
        for (int r = 0; r < 4; ++r) sv[s][ni][r] = -FM;
    __builtin_amdgcn_s_setprio(1);
#pragma unroll
    for (int ks = 0; ks < 8; ++ks) {
      i64 kf[2];
#pragma unroll
      for (int ni = 0; ni < 2; ++ni) {
        int row = ni * 16 + lo;
        int byteoff = row * 256 + ((((ks * 2 + (hi >> 1)) << 4) ^ ((row & 7) << 4))) + ((hi & 1) << 3);
        kf[ni] = *(const i64*)((const char*)&Kl[cur][0] + byteoff);
      }
#pragma unroll
      for (int s = 0; s < 2; ++s)
#pragma unroll
        for (int ni = 0; ni < 2; ++ni)
          sv[s][ni] = __builtin_amdgcn_mfma_f32_16x16x32_fp8_fp8(kf[ni], qf[s][ks], sv[s][ni], 0, 0, 0);
    }
    __builtin_amdgcn_s_setprio(0);
    // P = exp2(S^T - FM); lane covers keys {ni*16 + hi*4 + r} for q = s*16+lo.
    float p0[2][2][4];
#pragma unroll
    for (int ni = 0; ni < 2; ++ni) {
      ushort4 fgu = *(const ushort4*)&fgl[it * 32 + ni * 16 + hi * 4];
      float fg0 = bf2f(fgu.x), fg1 = bf2f(fgu.y), fg2 = bf2f(fgu.z), fg3 = bf2f(fgu.w);
#pragma unroll
      for (int s = 0; s < 2; ++s) {
        float e0 = exp2f(sv[s][ni][0]);
        float e1 = exp2f(sv[s][ni][1]);
        float e2 = exp2f(sv[s][ni][2]);
        float e3 = exp2f(sv[s][ni][3]);
        lsum[s] += e0 * fg0 + e1 * fg1 + e2 * fg2 + e3 * fg3;
        p0[s][ni][0] = e0; p0[s][ni][1] = e1; p0[s][ni][2] = e2; p0[s][ni][3] = e3;
      }
    }
    // P^T -> PV B-fragment in registers
    bf16x8 pbf[2];
#pragma unroll
    for (int s = 0; s < 2; ++s) {
      unsigned int pk00, pk01, pk10, pk11;
      asm("v_cvt_pk_bf16_f32 %0, %1, %2" : "=v"(pk00) : "v"(p0[s][0][0]), "v"(p0[s][0][1]));
      asm("v_cvt_pk_bf16_f32 %0, %1, %2" : "=v"(pk01) : "v"(p0[s][0][2]), "v"(p0[s][0][3]));
      asm("v_cvt_pk_bf16_f32 %0, %1, %2" : "=v"(pk10) : "v"(p0[s][1][0]), "v"(p0[s][1][1]));
      asm("v_cvt_pk_bf16_f32 %0, %1, %2" : "=v"(pk11) : "v"(p0[s][1][2]), "v"(p0[s][1][3]));
      int a00 = __shfl((int)pk00, srcA); int a10 = __shfl((int)pk10, srcA);
      int a01 = __shfl((int)pk01, srcA); int a11 = __shfl((int)pk11, srcA);
      int b00 = __shfl((int)pk00, srcB); int b10 = __shfl((int)pk10, srcB);
      int b01 = __shfl((int)pk01, srcB); int b11 = __shfl((int)pk11, srcB);
      u32x4 tv;
      tv.x = (unsigned)(hi < 2 ? a00 : a10);
      tv.y = (unsigned)(hi < 2 ? a01 : a11);
      tv.z = (unsigned)(hi < 2 ? b00 : b10);
      tv.w = (unsigned)(hi < 2 ? b01 : b11);
      pbf[s] = __builtin_bit_cast(bf16x8, tv);
    }
    // PV^T: A = V^T-frag, B = P^T
    __builtin_amdgcn_s_setprio(1);
#pragma unroll
    for (int cf = 0; cf < 16; ++cf) {
      int row = cf * 16 + lo;
      const char* vp = (const char*)&Vl[cur][0] + row * 64 + ((hi ^ (lo & 3) ^ ((lo >> 2) & 3)) << 4);
      bf16x8 vb = *(const bf16x8*)vp;
#pragma unroll
      for (int s = 0; s < 2; ++s)
        acc[s][cf] = __builtin_amdgcn_mfma_f32_16x16x32_bf16(vb, pbf[s], acc[s][cf], 0, 0, 0);
    }
    __builtin_amdgcn_s_setprio(0);
    __syncthreads();   // drains next-tile stage loads + all waves done with buf[cur]
  }
  // l reduction over the 4 hi-groups (lanes differing in bits 4,5 share q=lo)
  float ls[2];
#pragma unroll
  for (int s = 0; s < 2; ++s) {
    float t = lsum[s];
    t += __shfl_xor(t, 16);
    t += __shfl_xor(t, 32);
    ls[s] = t;
  }
  // epilogue: bf16 unnormalized partials (out^T regs -> row-major [q][d] stores) + (FM, l)
  u16* pb = pacc + (((size_t)s_k * BATCH + b) * NTOK + n0) * CDIM;
  float2* pm = pml + ((size_t)s_k * BATCH + b) * NTOK + n0;
#pragma unroll
  for (int s = 0; s < 2; ++s) {
#pragma unroll
    for (int cf = 0; cf < 16; ++cf) {
      ushort4 st;
      st.x = f2bf(acc[s][cf][0]);
      st.y = f2bf(acc[s][cf][1]);
      st.z = f2bf(acc[s][cf][2]);
      st.w = f2bf(acc[s][cf][3]);
      *(ushort4*)&pb[(size_t)(s * 16 + lo) * CDIM + cf * 16 + hi * 4] = st;
    }
    if (lane < 16) {
      float2 v; v.x = FM; v.y = ls[s];
      pm[s * 16 + lane] = v;
    }
  }
}

// ---------------- K5: fused combine(4 splits) + projection (gload_lds A-staging) ----------------
__global__ __launch_bounds__(256) void k_proj(const u16* __restrict__ pacc,
                                              const float2* __restrict__ pml,
                                              const u16* __restrict__ wp,
                                              const float* __restrict__ bproj, float* __restrict__ out) {
  __shared__ u16 Al[128 * 64];   // 16KB, chunk ^= (row&7)
  __shared__ u16 Bl[128][72];
  __shared__ float invl[128];
  const size_t RN = (size_t)BATCH * NTOK;
  int n0 = blockIdx.x * 128;
  int c0 = blockIdx.y * 128;
  int b  = blockIdx.z;
  int tid = threadIdx.x;
  int lane = tid & 63, w = tid >> 6;
  int lo = lane & 15, hi = lane >> 4;
  int wm = w >> 1, wn = w & 1;
  if (tid < 128) {
    float d = 0.0f;
#pragma unroll
    for (int s = 0; s < 4; ++s)
      d += pml[(size_t)s * RN + (size_t)b * NTOK + n0 + tid].y;
    invl[tid] = 1.0f / d;
  }
  f32x4 acc[4][4] = {};
  const u16* Ab = wp + (size_t)c0 * CDIM;
  for (int kcs = 0; kcs < 256; kcs += 64) {
    __syncthreads();
    // A via global_load_lds (1 inst/wave x 4)
#pragma unroll
    for (int j = 0; j < 4; ++j) {
      int id = (j * 4 + w) * 64 + lane;
      int row = id >> 3, c = id & 7;
      int sc = c ^ (row & 7);
      gload_lds16(Ab + (size_t)row * CDIM + kcs + sc * 8, &Al[(size_t)id * 8]);
    }
    // B: sum 4 bf16 splits of pacc, scale by 1/l, back to bf16 (reg-staged)
#pragma unroll
    for (int i = 0; i < 4; ++i) {
      int cid = i * 256 + tid;
      int row = cid >> 3, cc = cid & 7;
      size_t off = ((size_t)b * NTOK + n0 + row) * CDIM + kcs + cc * 8;
      float v[8] = {0, 0, 0, 0, 0, 0, 0, 0};
#pragma unroll
      for (int s = 0; s < 4; ++s) {
        uint4 u = *(const uint4*)(pacc + (size_t)s * RN * CDIM + off);
        const u16* pu = (const u16*)&u;
#pragma unroll
        for (int j = 0; j < 8; ++j) v[j] += bf2f(pu[j]);
      }
      float iv = invl[row];
      ushort4 o0, o1;
      o0.x = f2bf(v[0] * iv); o0.y = f2bf(v[1] * iv); o0.z = f2bf(v[2] * iv); o0.w = f2bf(v[3] * iv);
      o1.x = f2bf(v[4] * iv); o1.y = f2bf(v[5] * iv); o1.z = f2bf(v[6] * iv); o1.w = f2bf(v[7] * iv);
      *(ushort4*)&Bl[row][cc * 8]     = o0;
      *(ushort4*)&Bl[row][cc * 8 + 4] = o1;
    }
    __syncthreads();
#pragma unroll
    for (int kk = 0; kk < 2; ++kk) {
      bf16x8 af[4], bfr[4];
#pragma unroll
      for (int mi = 0; mi < 4; ++mi) {
        int row = wm * 64 + mi * 16 + lo;
        af[mi] = *(const bf16x8*)&Al[row * 64 + (((kk * 4 + hi) ^ (row & 7)) * 8)];
      }
#pragma unroll
      for (int ni = 0; ni < 4; ++ni) bfr[ni] = *(const bf16x8*)&Bl[wn * 64 + ni * 16 + lo][kk * 32 + hi * 8];
#pragma unroll
      for (int mi = 0; mi < 4; ++mi)
#pragma unroll
        for (int ni = 0; ni < 4; ++ni)
          acc[mi][ni] = __builtin_amdgcn_mfma_f32_16x16x32_bf16(af[mi], bfr[ni], acc[mi][ni], 0, 0, 0);
    }
  }
#pragma unroll
  for (int mi = 0; mi < 4; ++mi) {
    int cbase = c0 + wm * 64 + mi * 16 + hi * 4;
#pragma unroll
    for (int r = 0; r < 4; ++r) {
      float bias = bproj[cbase + r];
#pragma unroll
      for (int ni = 0; ni < 4; ++ni) {
        int n = n0 + wn * 64 + ni * 16 + lo;
        out[((size_t)b * CDIM + cbase + r) * NTOK + n] = acc[mi][ni][r] + bias;
      }
    }
  }
}

extern "C" void kernel_launch(void* const* d_in, const int* in_sizes, int n_in,
                              void* d_out, int out_size, void* d_ws, size_t ws_size,
                              hipStream_t stream) {
  const float* x     = (const float*)d_in[0];
  const int*   fg    = (const int*)d_in[1];
  const float* Wqkv  = (const float*)d_in[2];
  const float* Wproj = (const float*)d_in[3];
  const float* bproj = (const float*)d_in[4];
  float* out = (float*)d_out;
  char* ws = (char*)d_ws;
  u16*   xbf  = (u16*)(ws);                    // 8388608 B
  u8*    Qm8  = (u8*)(ws + 8388608);           // 4194304
  u8*    Km8  = (u8*)(ws + 12582912);          // 4194304
  u16*   Vt   = (u16*)(ws + 16777216);         // 272*4096*2*4 = 8912896
  u16*   wq   = (u16*)(ws + 25690112);         // 393216
  u16*   wp   = (u16*)(ws + 26083328);         // 131072  -> ends 26214400
  u16*   pacc = (u16*)(ws + 26214400);         // 4 x 8 MiB bf16 = 33554432 -> ends 59768832
  float2* pml = (float2*)(ws + 59768832);      // 512 KiB -> ends 60293120

  k_prep<<<1088, 256, 0, stream>>>(Wqkv, Wproj, fg, wq, wp, Vt);
  k_transpose<<<dim3(64, 4, 4), 256, 0, stream>>>(x, xbf);
  k_qkv<<<dim3(32, 6, 4), 256, 0, stream>>>(xbf, wq, fg, Qm8, Km8, Vt);
  k_attn<<<512, 256, 0, stream>>>(Qm8, Km8, Vt, pacc, pml, 2);
  k_proj<<<dim3(32, 2, 4), 256, 0, stream>>>(pacc, pml, wp, bproj, out);
}

// Round 17
// 138.447 us; speedup vs baseline: 2.3359x; 1.0021x over previous
//
#include <hip/hip_runtime.h>
#include <hip/hip_bf16.h>

#define BATCH 4
#define CDIM  256
#define NTOK  4096
#define THREE (3*CDIM)
#define VROWS 272   // 256 V channels + fg row at 256 (257..271 unused)

typedef unsigned short u16;
typedef unsigned char u8;
typedef long i64;
typedef __attribute__((ext_vector_type(4))) float f32x4;
typedef __attribute__((ext_vector_type(8))) short bf16x8;
typedef __attribute__((ext_vector_type(4))) unsigned int u32x4;

#define AS1 __attribute__((address_space(1)))
#define AS3 __attribute__((address_space(3)))

__device__ __forceinline__ u16 f2bf(float x) {
  unsigned int u = __float_as_uint(x);
  unsigned int r = (u + 0x7fffu + ((u >> 16) & 1u)) >> 16;   // RTNE
  return (u16)r;
}
__device__ __forceinline__ float bf2f(u16 v) {
  return __uint_as_float(((unsigned int)v) << 16);
}
__device__ __forceinline__ u8 f2fp8(float x) {
  int r = __builtin_amdgcn_cvt_pk_fp8_f32(x, 0.0f, 0, false);  // e4m3 (OCP), RNE
  return (u8)(r & 0xff);
}
__device__ __forceinline__ void gload_lds16(const void* g, void* l) {
  __builtin_amdgcn_global_load_lds((AS1 const void*)g, (AS3 void*)l, 16, 0, 0);
}

// both Q and K carry sqrt(log2e/16) so (Q'.K') is directly in log2 domain
#define SC8 0.30028132f

// ---------------- K1: weights -> bf16; fg -> bf16 row in Vt ----------------
__global__ void k_prep(const float* __restrict__ Wqkv, const float* __restrict__ Wproj,
                       const int* __restrict__ fg,
                       u16* __restrict__ wq, u16* __restrict__ wp,
                       u16* __restrict__ Vt) {
  int i = blockIdx.x * 256 + threadIdx.x;
  const int nq = THREE * CDIM;          // 196608
  const int np = CDIM * CDIM;           // 65536
  const int nf = BATCH * NTOK;          // 16384 (fg row c=256)
  if (i < nq) { wq[i] = f2bf(Wqkv[i]); return; }
  int j = i - nq;
  if (j < np) { wp[j] = f2bf(Wproj[j]); return; }
  int k = j - np;
  if (k < nf) {
    int b = k >> 12, key = k & (NTOK - 1);
    Vt[((size_t)b * VROWS + 256) * NTOK + key] = fg[k] ? 0x3F80 : 0;  // bf16 1.0/0.0
  }
}

// ---------------- K2: x [B][C][N] f32 -> xbf [B][N][C] bf16 (vectorized) ----------------
// float4 loads (16B/lane), f32 LDS tile [64][66] (+2 pad), ushort4 stores (8B/lane).
__global__ __launch_bounds__(256) void k_transpose(const float* __restrict__ x, u16* __restrict__ xbf) {
  __shared__ float Ts[64][66];
  int n0 = blockIdx.x * 64;
  int c0 = blockIdx.y * 64;
  int b  = blockIdx.z;
  int tid = threadIdx.x;
  const float* xp = x + (size_t)b * CDIM * NTOK;
  int g16 = tid >> 4;          // 0..15
  int l16 = tid & 15;          // 0..15
#pragma unroll
  for (int i = 0; i < 4; ++i) {
    int cl = i * 16 + g16;
    int n4 = l16 * 4;
    *(f32x4*)&Ts[cl][n4] = *(const f32x4*)(xp + (size_t)(c0 + cl) * NTOK + n0 + n4);
  }
  __syncthreads();
#pragma unroll
  for (int i = 0; i < 4; ++i) {
    int nl = i * 16 + g16;
    int c4 = l16 * 4;
    ushort4 o;
    o.x = f2bf(Ts[c4 + 0][nl]);
    o.y = f2bf(Ts[c4 + 1][nl]);
    o.z = f2bf(Ts[c4 + 2][nl]);
    o.w = f2bf(Ts[c4 + 3][nl]);
    *(ushort4*)&xbf[((size_t)b * NTOK + n0 + nl) * CDIM + c0 + c4] = o;
  }
}

// ---------------- K3: qkv GEMM (gload_lds staging). Q,K -> fp8 e4m3 (x SC8); V^T bf16, fg-zeroed ----------------
// A/B tiles staged via global_load_lds: linear LDS [128 rows x 128B], 16B chunk c
// holds global chunk c^(row&7); reads use the same XOR (2-way banks, free).
__global__ __launch_bounds__(256) void k_qkv(const u16* __restrict__ xbf, const u16* __restrict__ wq,
                                             const int* __restrict__ fg,
                                             u8* __restrict__ Qm8, u8* __restrict__ Km8,
                                             u16* __restrict__ Vt) {
  __shared__ u16 Al[128 * 64];   // 16KB
  __shared__ u16 Bl[128 * 64];   // 16KB
  int n0 = blockIdx.x * 128;
  int d0 = blockIdx.y * 128;
  int b  = blockIdx.z;
  int tid = threadIdx.x;
  int lane = tid & 63, w = tid >> 6;
  int lo = lane & 15, hi = lane >> 4;
  int wm = w >> 1, wn = w & 1;
  f32x4 acc[4][4] = {};
  const u16* Ab = xbf + ((size_t)b * NTOK + n0) * CDIM;
  const u16* Bb = wq + (size_t)d0 * CDIM;
  for (int kc = 0; kc < 256; kc += 64) {
    __syncthreads();
#pragma unroll
    for (int j = 0; j < 4; ++j) {
      int id = (j * 4 + w) * 64 + lane;     // 0..1023 16B-chunks
      int row = id >> 3, c = id & 7;
      int sc = c ^ (row & 7);               // source pre-swizzle
      gload_lds16(Ab + (size_t)row * CDIM + kc + sc * 8, &Al[(size_t)id * 8]);
      gload_lds16(Bb + (size_t)row * CDIM + kc + sc * 8, &Bl[(size_t)id * 8]);
    }
    __syncthreads();
#pragma unroll
    for (int kk = 0; kk < 2; ++kk) {
      bf16x8 af[4], bfr[4];
#pragma unroll
      for (int mi = 0; mi < 4; ++mi) {
        int row = wm * 64 + mi * 16 + lo;
        af[mi] = *(const bf16x8*)&Al[row * 64 + (((kk * 4 + hi) ^ (row & 7)) * 8)];
      }
#pragma unroll
      for (int ni = 0; ni < 4; ++ni) {
        int row = wn * 64 + ni * 16 + lo;
        bfr[ni] = *(const bf16x8*)&Bl[row * 64 + (((kk * 4 + hi) ^ (row & 7)) * 8)];
      }
#pragma unroll
      for (int mi = 0; mi < 4; ++mi)
#pragma unroll
        for (int ni = 0; ni < 4; ++ni)
          acc[mi][ni] = __builtin_amdgcn_mfma_f32_16x16x32_bf16(af[mi], bfr[ni], acc[mi][ni], 0, 0, 0);
    }
  }
  int seg = d0 >> 8;   // 0=Q 1=K 2=V
#pragma unroll
  for (int mi = 0; mi < 4; ++mi) {
    int nbase = n0 + wm * 64 + mi * 16 + hi * 4;
#pragma unroll
    for (int ni = 0; ni < 4; ++ni) {
      int d = d0 + wn * 64 + ni * 16 + lo;
      if (seg == 0) {
#pragma unroll
        for (int r = 0; r < 4; ++r)
          Qm8[((size_t)b * NTOK + nbase + r) * CDIM + d] = f2fp8(acc[mi][ni][r] * SC8);
      } else if (seg == 1) {
        int dk = d - 256;
#pragma unroll
        for (int r = 0; r < 4; ++r)
          Km8[((size_t)b * NTOK + nbase + r) * CDIM + dk] = f2fp8(acc[mi][ni][r] * SC8);
      } else {
        int dv = d - 512;
        ushort4 pk;
        pk.x = fg[b * NTOK + nbase + 0] ? f2bf(acc[mi][ni][0]) : (u16)0;
        pk.y = fg[b * NTOK + nbase + 1] ? f2bf(acc[mi][ni][1]) : (u16)0;
        pk.z = fg[b * NTOK + nbase + 2] ? f2bf(acc[mi][ni][2]) : (u16)0;
        pk.w = fg[b * NTOK + nbase + 3] ? f2bf(acc[mi][ni][3]) : (u16)0;
        *(ushort4*)&Vt[((size_t)b * VROWS + dv) * NTOK + nbase] = pk;
      }
    }
  }
}

// ---------------- K4: flash attention, fp8 QK, R13 schedule (split-4, 2 blocks/CU) ----------------
// grid = 512 blocks; 4 waves x 32 q-rows; KBLK=32; double-buffered staging; LDS 50KB.
// S^T = mfma_fp8(K',Q') directly in log2 domain; P^T in registers (cvt_pk+shfl);
// PV^T = mfma(V^T, P^T) bf16. Fixed max FM=12; mask via zeroed V rows; l = sum P*fg.
__global__ __launch_bounds__(256, 2) void k_attn(const u8* __restrict__ Qm8, const u8* __restrict__ Km8,
                                                 const u16* __restrict__ Vt,
                                                 u16* __restrict__ pacc, float2* __restrict__ pml,
                                                 int lsplit) {
  __shared__ u8  Kl[2][32 * 256];    // 8KB x2 fp8; 16B-chunk ^= (row&7)
  __shared__ u16 Vl[2][256 * 32];    // 16KB x2 bf16; chunk ^= (row&3)^((row>>2)&3)
  __shared__ u16 fgl[1024];          // bf16 fg for this chunk's 1024 keys
  const float FM = 12.0f;
  int nwg = gridDim.x;
  int cpx = nwg >> 3;
  int orig = blockIdx.x;
  int wg = (orig & 7) * cpx + (orig >> 3);   // bijective XCD swizzle (nwg % 8 == 0)
  int qt = wg & 31;
  int bs = wg >> 5;
  int s_k = bs & ((1 << lsplit) - 1);
  int b   = bs >> lsplit;
  int chunk = NTOK >> lsplit;                // 1024
  int koff  = s_k * chunk;
  int iters = chunk >> 5;                    // 32

  int tid = threadIdx.x;
  int lane = tid & 63, w = tid >> 6;
  int lo = lane & 15, hi = lane >> 4;
  int n0 = qt * 128 + w * 32;
  // Q': 32 rows x 256 fp8 in registers (16 VGPR)
  i64 qf[2][8];
#pragma unroll
  for (int s = 0; s < 2; ++s) {
    const u8* qp = Qm8 + ((size_t)b * NTOK + n0 + s * 16 + lo) * CDIM + hi * 8;
#pragma unroll
    for (int ks = 0; ks < 8; ++ks) qf[s][ks] = *(const i64*)(qp + ks * 32);
  }
  f32x4 acc[2][16] = {};   // out^T: acc[s][cf][r] = out[d=cf*16+hi*4+r][q=s*16+lo]
  float lsum[2] = {0.0f, 0.0f};
  const u8*  kbase = Km8 + (size_t)b * NTOK * CDIM;
  const u16* vbase = Vt + (size_t)b * VROWS * NTOK;
  const u16* fgrow = vbase + (size_t)256 * NTOK;   // bf16 fg row
  int vr  = lane >> 2;   // V staging: row within 16-row group
  int vc  = lane & 3;
  int srcA = lo + ((hi & 1) << 5);   // P^T exchange source lanes
  int srcB = srcA + 16;

  // stage K (2 insts/wave, fp8) and V (4 insts/wave) for key-block m0 into buffer buf
  auto stage = [&](int buf, int m0) {
#pragma unroll
    for (int j = 0; j < 2; ++j) {
      int rl = w * 8 + j * 4 + (lane >> 4);          // row within 32-row tile
      int sb = ((lane & 15) << 4) ^ ((rl & 7) << 4); // source pre-swizzle (16B chunks)
      gload_lds16(kbase + (size_t)(m0 + rl) * CDIM + sb,
                  &Kl[buf][w * 2048 + j * 1024]);
    }
#pragma unroll
    for (int j = 0; j < 4; ++j) {
      int idx = j * 4 + w;                 // 0..15
      int r = idx * 16 + vr;
      int d = vc ^ (r & 3) ^ ((r >> 2) & 3);
      gload_lds16(vbase + (size_t)r * NTOK + m0 + d * 8, &Vl[buf][idx * 512]);
    }
  };

  // prologue: fg chunk (waves 0,1: dest base is lane0's ptr + lane*16B) + tile 0
  if (w < 2) gload_lds16(fgrow + koff + w * 512 + lane * 8, &fgl[w * 512 + lane * 8]);
  stage(0, koff);
  __syncthreads();
  for (int it = 0; it < iters; ++it) {
    int cur = it & 1;
    int m0 = koff + it * 32;
    if (it + 1 < iters) stage(cur ^ 1, m0 + 32);   // prefetch next tile
    // S^T - FM: A = K' (fp8), B = Q' (fp8), scales pre-folded to log2 domain
    f32x4 sv[2][2];
#pragma unroll
    for (int s = 0; s < 2; ++s)
#pragma unroll
      for (int ni = 0; ni < 2; ++ni)
#pragma unroll
        for (int r = 0; r < 4; ++r) sv[s][ni][r] = -FM;
    __builtin_amdgcn_s_setprio(1);
#pragma unroll
    for (int ks = 0; ks < 8; ++ks) {
      i64 kf[2];
#pragma unroll
      for (int ni = 0; ni < 2; ++ni) {
        int row = ni * 16 + lo;
        int byteoff = row * 256 + ((((ks * 2 + (hi >> 1)) << 4) ^ ((row & 7) << 4))) + ((hi & 1) << 3);
        kf[ni] = *(const i64*)((const char*)&Kl[cur][0] + byteoff);
      }
#pragma unroll
      for (int s = 0; s < 2; ++s)
#pragma unroll
        for (int ni = 0; ni < 2; ++ni)
          sv[s][ni] = __builtin_amdgcn_mfma_f32_16x16x32_fp8_fp8(kf[ni], qf[s][ks], sv[s][ni], 0, 0, 0);
    }
    __builtin_amdgcn_s_setprio(0);
    // P = exp2(S^T - FM); lane covers keys {ni*16 + hi*4 + r} for q = s*16+lo.
    float p0[2][2][4];
#pragma unroll
    for (int ni = 0; ni < 2; ++ni) {
      ushort4 fgu = *(const ushort4*)&fgl[it * 32 + ni * 16 + hi * 4];
      float fg0 = bf2f(fgu.x), fg1 = bf2f(fgu.y), fg2 = bf2f(fgu.z), fg3 = bf2f(fgu.w);
#pragma unroll
      for (int s = 0; s < 2; ++s) {
        float e0 = exp2f(sv[s][ni][0]);
        float e1 = exp2f(sv[s][ni][1]);
        float e2 = exp2f(sv[s][ni][2]);
        float e3 = exp2f(sv[s][ni][3]);
        lsum[s] += e0 * fg0 + e1 * fg1 + e2 * fg2 + e3 * fg3;
        p0[s][ni][0] = e0; p0[s][ni][1] = e1; p0[s][ni][2] = e2; p0[s][ni][3] = e3;
      }
    }
    // P^T -> PV B-fragment in registers
    bf16x8 pbf[2];
#pragma unroll
    for (int s = 0; s < 2; ++s) {
      unsigned int pk00, pk01, pk10, pk11;
      asm("v_cvt_pk_bf16_f32 %0, %1, %2" : "=v"(pk00) : "v"(p0[s][0][0]), "v"(p0[s][0][1]));
      asm("v_cvt_pk_bf16_f32 %0, %1, %2" : "=v"(pk01) : "v"(p0[s][0][2]), "v"(p0[s][0][3]));
      asm("v_cvt_pk_bf16_f32 %0, %1, %2" : "=v"(pk10) : "v"(p0[s][1][0]), "v"(p0[s][1][1]));
      asm("v_cvt_pk_bf16_f32 %0, %1, %2" : "=v"(pk11) : "v"(p0[s][1][2]), "v"(p0[s][1][3]));
      int a00 = __shfl((int)pk00, srcA); int a10 = __shfl((int)pk10, srcA);
      int a01 = __shfl((int)pk01, srcA); int a11 = __shfl((int)pk11, srcA);
      int b00 = __shfl((int)pk00, srcB); int b10 = __shfl((int)pk10, srcB);
      int b01 = __shfl((int)pk01, srcB); int b11 = __shfl((int)pk11, srcB);
      u32x4 tv;
      tv.x = (unsigned)(hi < 2 ? a00 : a10);
      tv.y = (unsigned)(hi < 2 ? a01 : a11);
      tv.z = (unsigned)(hi < 2 ? b00 : b10);
      tv.w = (unsigned)(hi < 2 ? b01 : b11);
      pbf[s] = __builtin_bit_cast(bf16x8, tv);
    }
    // PV^T: A = V^T-frag, B = P^T
    __builtin_amdgcn_s_setprio(1);
#pragma unroll
    for (int cf = 0; cf < 16; ++cf) {
      int row = cf * 16 + lo;
      const char* vp = (const char*)&Vl[cur][0] + row * 64 + ((hi ^ (lo & 3) ^ ((lo >> 2) & 3)) << 4);
      bf16x8 vb = *(const bf16x8*)vp;
#pragma unroll
      for (int s = 0; s < 2; ++s)
        acc[s][cf] = __builtin_amdgcn_mfma_f32_16x16x32_bf16(vb, pbf[s], acc[s][cf], 0, 0, 0);
    }
    __builtin_amdgcn_s_setprio(0);
    __syncthreads();   // drains next-tile stage loads + all waves done with buf[cur]
  }
  // l reduction over the 4 hi-groups (lanes differing in bits 4,5 share q=lo)
  float ls[2];
#pragma unroll
  for (int s = 0; s < 2; ++s) {
    float t = lsum[s];
    t += __shfl_xor(t, 16);
    t += __shfl_xor(t, 32);
    ls[s] = t;
  }
  // epilogue: bf16 unnormalized partials (out^T regs -> row-major [q][d] stores) + (FM, l)
  u16* pb = pacc + (((size_t)s_k * BATCH + b) * NTOK + n0) * CDIM;
  float2* pm = pml + ((size_t)s_k * BATCH + b) * NTOK + n0;
#pragma unroll
  for (int s = 0; s < 2; ++s) {
#pragma unroll
    for (int cf = 0; cf < 16; ++cf) {
      ushort4 st;
      st.x = f2bf(acc[s][cf][0]);
      st.y = f2bf(acc[s][cf][1]);
      st.z = f2bf(acc[s][cf][2]);
      st.w = f2bf(acc[s][cf][3]);
      *(ushort4*)&pb[(size_t)(s * 16 + lo) * CDIM + cf * 16 + hi * 4] = st;
    }
    if (lane < 16) {
      float2 v; v.x = FM; v.y = ls[s];
      pm[s * 16 + lane] = v;
    }
  }
}

// ---------------- K5: fused combine(4 splits) + projection (gload_lds A-staging) ----------------
__global__ __launch_bounds__(256) void k_proj(const u16* __restrict__ pacc,
                                              const float2* __restrict__ pml,
                                              const u16* __restrict__ wp,
                                              const float* __restrict__ bproj, float* __restrict__ out) {
  __shared__ u16 Al[128 * 64];   // 16KB, chunk ^= (row&7)
  __shared__ u16 Bl[128][72];
  __shared__ float invl[128];
  const size_t RN = (size_t)BATCH * NTOK;
  int n0 = blockIdx.x * 128;
  int c0 = blockIdx.y * 128;
  int b  = blockIdx.z;
  int tid = threadIdx.x;
  int lane = tid & 63, w = tid >> 6;
  int lo = lane & 15, hi = lane >> 4;
  int wm = w >> 1, wn = w & 1;
  if (tid < 128) {
    float d = 0.0f;
#pragma unroll
    for (int s = 0; s < 4; ++s)
      d += pml[(size_t)s * RN + (size_t)b * NTOK + n0 + tid].y;
    invl[tid] = 1.0f / d;
  }
  f32x4 acc[4][4] = {};
  const u16* Ab = wp + (size_t)c0 * CDIM;
  for (int kcs = 0; kcs < 256; kcs += 64) {
    __syncthreads();
    // A via global_load_lds (1 inst/wave x 4)
#pragma unroll
    for (int j = 0; j < 4; ++j) {
      int id = (j * 4 + w) * 64 + lane;
      int row = id >> 3, c = id & 7;
      int sc = c ^ (row & 7);
      gload_lds16(Ab + (size_t)row * CDIM + kcs + sc * 8, &Al[(size_t)id * 8]);
    }
    // B: sum 4 bf16 splits of pacc, scale by 1/l, back to bf16 (reg-staged)
#pragma unroll
    for (int i = 0; i < 4; ++i) {
      int cid = i * 256 + tid;
      int row = cid >> 3, cc = cid & 7;
      size_t off = ((size_t)b * NTOK + n0 + row) * CDIM + kcs + cc * 8;
      float v[8] = {0, 0, 0, 0, 0, 0, 0, 0};
#pragma unroll
      for (int s = 0; s < 4; ++s) {
        uint4 u = *(const uint4*)(pacc + (size_t)s * RN * CDIM + off);
        const u16* pu = (const u16*)&u;
#pragma unroll
        for (int j = 0; j < 8; ++j) v[j] += bf2f(pu[j]);
      }
      float iv = invl[row];
      ushort4 o0, o1;
      o0.x = f2bf(v[0] * iv); o0.y = f2bf(v[1] * iv); o0.z = f2bf(v[2] * iv); o0.w = f2bf(v[3] * iv);
      o1.x = f2bf(v[4] * iv); o1.y = f2bf(v[5] * iv); o1.z = f2bf(v[6] * iv); o1.w = f2bf(v[7] * iv);
      *(ushort4*)&Bl[row][cc * 8]     = o0;
      *(ushort4*)&Bl[row][cc * 8 + 4] = o1;
    }
    __syncthreads();
#pragma unroll
    for (int kk = 0; kk < 2; ++kk) {
      bf16x8 af[4], bfr[4];
#pragma unroll
      for (int mi = 0; mi < 4; ++mi) {
        int row = wm * 64 + mi * 16 + lo;
        af[mi] = *(const bf16x8*)&Al[row * 64 + (((kk * 4 + hi) ^ (row & 7)) * 8)];
      }
#pragma unroll
      for (int ni = 0; ni < 4; ++ni) bfr[ni] = *(const bf16x8*)&Bl[wn * 64 + ni * 16 + lo][kk * 32 + hi * 8];
#pragma unroll
      for (int mi = 0; mi < 4; ++mi)
#pragma unroll
        for (int ni = 0; ni < 4; ++ni)
          acc[mi][ni] = __builtin_amdgcn_mfma_f32_16x16x32_bf16(af[mi], bfr[ni], acc[mi][ni], 0, 0, 0);
    }
  }
#pragma unroll
  for (int mi = 0; mi < 4; ++mi) {
    int cbase = c0 + wm * 64 + mi * 16 + hi * 4;
#pragma unroll
    for (int r = 0; r < 4; ++r) {
      float bias = bproj[cbase + r];
#pragma unroll
      for (int ni = 0; ni < 4; ++ni) {
        int n = n0 + wn * 64 + ni * 16 + lo;
        out[((size_t)b * CDIM + cbase + r) * NTOK + n] = acc[mi][ni][r] + bias;
      }
    }
  }
}

extern "C" void kernel_launch(void* const* d_in, const int* in_sizes, int n_in,
                              void* d_out, int out_size, void* d_ws, size_t ws_size,
                              hipStream_t stream) {
  const float* x     = (const float*)d_in[0];
  const int*   fg    = (const int*)d_in[1];
  const float* Wqkv  = (const float*)d_in[2];
  const float* Wproj = (const float*)d_in[3];
  const float* bproj = (const float*)d_in[4];
  float* out = (float*)d_out;
  char* ws = (char*)d_ws;
  u16*   xbf  = (u16*)(ws);                    // 8388608 B
  u8*    Qm8  = (u8*)(ws + 8388608);           // 4194304
  u8*    Km8  = (u8*)(ws + 12582912);          // 4194304
  u16*   Vt   = (u16*)(ws + 16777216);         // 272*4096*2*4 = 8912896
  u16*   wq   = (u16*)(ws + 25690112);         // 393216
  u16*   wp   = (u16*)(ws + 26083328);         // 131072  -> ends 26214400
  u16*   pacc = (u16*)(ws + 26214400);         // 4 x 8 MiB bf16 = 33554432 -> ends 59768832
  float2* pml = (float2*)(ws + 59768832);      // 512 KiB -> ends 60293120

  k_prep<<<1088, 256, 0, stream>>>(Wqkv, Wproj, fg, wq, wp, Vt);
  k_transpose<<<dim3(64, 4, 4), 256, 0, stream>>>(x, xbf);
  k_qkv<<<dim3(32, 6, 4), 256, 0, stream>>>(xbf, wq, fg, Qm8, Km8, Vt);
  k_attn<<<512, 256, 0, stream>>>(Qm8, Km8, Vt, pacc, pml, 2);
  k_proj<<<dim3(32, 2, 4), 256, 0, stream>>>(pacc, pml, wp, bproj, out);
}